// Round 1
// baseline (40.421 us; speedup 1.0000x reference)
//
#include <hip/hip_runtime.h>
#include <hip/hip_bf16.h>

#define NSITES 4096  // 64 x 64

// Scatter the nonzero Hamiltonian entries.
// Work layout: 4 H's x (2048 padded bulk slots + 32 twist slots) = 8320 items.
// comps = 2 -> interleaved (re, im) float32 layout; comps = 1 -> real-only.
__global__ void tb_floquet_scatter(const float* __restrict__ thx_p,
                                   const float* __restrict__ thy_p,
                                   float* __restrict__ out, int comps) {
    const int PER_H = 2048 + 32;
    int t = blockIdx.x * blockDim.x + threadIdx.x;
    if (t >= 4 * PER_H) return;
    int h = t / PER_H;
    int idx = t - h * PER_H;
    float th = (h == 0 || h == 2) ? thy_p[0] : thx_p[0];
    long long base = (long long)h * NSITES * NSITES * comps;

    if (idx < 2048) {
        int r = -1, c = -1;
        if (h == 0) {
            // H1: a = 2j + (j>=32), b = a+64, repeated +128k
            int j = idx >> 5, k = idx & 31;
            int a = 2 * j + (j >= 32 ? 1 : 0) + 128 * k;
            int b = a + 64;
            if (b < NSITES) { r = a; c = b; }
        } else if (h == 1) {
            // H2: per 128-block, o in {1,3,..,61} u {64,66,..,126}, pair (a, a+1)
            int k = idx >> 6, i = idx & 63;
            if (k < 32 && i < 63) {
                int o = (i < 31) ? (2 * i + 1) : (2 * i + 2);
                r = 128 * k + o; c = r + 1;
            }
        } else if (h == 2) {
            // H3: row rr in [0,63): o odd if rr even else even, pair (a, a+64)
            int rr = idx >> 5, i = idx & 31;
            if (rr < 63) {
                r = 64 * rr + 2 * i + ((rr & 1) ? 0 : 1);
                c = r + 64;
            }
        } else {
            // H4: per 128-block, o in {0,2,..,62} u {65,67,..,125}, pair (a, a+1)
            int k = idx >> 6, i = idx & 63;
            if (k < 32 && i < 63) {
                int o = (i < 32) ? (2 * i) : (2 * i + 1);
                r = 128 * k + o; c = r + 1;
            }
        }
        if (r >= 0) {
            long long e1 = base + ((long long)r * NSITES + c) * comps;
            long long e2 = base + ((long long)c * NSITES + r) * comps;
            out[e1] = -1.0f;
            out[e2] = -1.0f;
            if (comps == 2) { out[e1 + 1] = 0.0f; out[e2 + 1] = 0.0f; }
        }
    } else {
        int p = idx - 2048;  // 0..31
        int tr, tc;
        if (h == 0)      { tr = 4033 + 2 * p; tc = 1 + 2 * p; }
        else if (h == 1) { tr = 63 + 128 * p; tc = 128 * p; }
        else if (h == 2) { tr = 4032 + 2 * p; tc = 2 * p; }
        else             { tr = 127 + 128 * p; tc = 64 + 128 * p; }
        float cr = -cosf(th);
        float ci = -sinf(th);
        long long e1 = base + ((long long)tr * NSITES + tc) * comps;
        long long e2 = base + ((long long)tc * NSITES + tr) * comps;
        out[e1] = cr;
        out[e2] = cr;
        if (comps == 2) { out[e1 + 1] = ci; out[e2 + 1] = -ci; }
    }
}

extern "C" void kernel_launch(void* const* d_in, const int* in_sizes, int n_in,
                              void* d_out, int out_size, void* d_ws, size_t ws_size,
                              hipStream_t stream) {
    const float* thx = (const float*)d_in[0];
    const float* thy = (const float*)d_in[1];
    float* out = (float*)d_out;

    // Zero the whole output (sparse matrices: ~0.006% nonzero).
    hipMemsetAsync(d_out, 0, (size_t)out_size * sizeof(float), stream);

    // comps: 2 if output is interleaved complex (re,im), 1 if real-only view.
    int comps = out_size / (4 * NSITES * NSITES);
    if (comps < 1) comps = 1;
    if (comps > 2) comps = 2;

    const int PER_H = 2048 + 32;
    int total = 4 * PER_H;
    int block = 256;
    int grid = (total + block - 1) / block;
    tb_floquet_scatter<<<grid, block, 0, stream>>>(thx, thy, out, comps);
}